// Round 9
// baseline (5449.681 us; speedup 1.0000x reference)
//
#include <hip/hip_runtime.h>
#include <stdint.h>

#define BATCH 4
#define NPTS  8192
#define CFEAT 64
#define MCENT 2048
#define NCENT (BATCH * MCENT)
#define KMAX  64
#define NEGV  -1e30f

// Exact-rounding squared distance, matching numpy's ((dx*dx+dy*dy)+dz*dz)
// with NO fma contraction (discrete neighbor selection requires bit parity).
__device__ __forceinline__ float dist2(float ax, float ay, float az,
                                       float bx, float by, float bz) {
    float dx = __fsub_rn(ax, bx);
    float dy = __fsub_rn(ay, by);
    float dz = __fsub_rn(az, bz);
    return __fadd_rn(__fadd_rn(__fmul_rn(dx, dx), __fmul_rn(dy, dy)),
                     __fmul_rn(dz, dz));
}

// DPP lane-permute helpers (VALU-latency cross-lane)
template <int CTRL>
__device__ __forceinline__ float dppf(float v) {
    return __int_as_float(__builtin_amdgcn_update_dpp(
        __float_as_int(v), __float_as_int(v), CTRL, 0xF, 0xF, false));
}
template <int CTRL>
__device__ __forceinline__ int dppi(int v) {
    return __builtin_amdgcn_update_dpp(v, v, CTRL, 0xF, 0xF, false);
}

// Monotone key: (fp32 bits of nonneg max) << 32 | (0x7FFFFFFF - arg).
// u64 max == (max value, then min arg) == jnp.argmax first-occurrence
// (arg = orig_idx<<13 | slot, orig_idx in high bits).
__device__ __forceinline__ unsigned long long packkey(float mx, int arg) {
    return ((unsigned long long)(unsigned int)__float_as_uint(mx) << 32)
         | (unsigned int)(0x7FFFFFFF - arg);
}

// ---------------------------------------------------------------------------
// Kernel 1: FPS. Rounds 7/8 post-mortem: multi-wave pruned iterations are
// pinned at ~1.6us/iter by the phase structure (3 barriers + dependent
// cross-wave LDS round trips), not by work. Round-9 structure:
//   - iters 0..127  : DENSE, 512 threads, full float2-pair scan + per-cell
//                     argmax + u64-key DPP block reduce (2 barriers/iter).
//   - handoff       : write per-cell u64 keys, barrier, waves 1..7 EXIT.
//   - iters 128..   : SPARSE, wave 0 only, ZERO barriers. Lane l owns 8
//                     cells c=(z<<6)|(l^z) (z-columns spread across lanes).
//                     Per iter: register-resident box prune vs cellkey-hi,
//                     ballot-compact survivors, quarter-wave(16-lane DPP row)
//                     per surviving cell exact mind update + argmax, u64 key
//                     write; global argmax = 8 key reads/lane + 6-step u64
//                     DPP max; winner broadcast via v_readlane.
// mind arithmetic is bit-identical to the unpruned version; pruning (0.9999
// deflated box lower bound) skips only provably-no-op cells. Empty cells
// pack to key 0 (red init 0.0f, NOT -1: negative fp bits are huge as uint).
// ---------------------------------------------------------------------------
#define FPS_T   512
#define NCELL   512
#define S_DENSE 128

__global__ __launch_bounds__(FPS_T, 2) void fps_kernel(const float* __restrict__ pos,
                                                       float* __restrict__ pos_s) {
    const int b = blockIdx.x;
    const float* pb = pos + b * NPTS * 3;
    const int t = threadIdx.x;          // 0..511
    const int w = t >> 6;               // wave id 0..7
    const int l = t & 63;               // lane id

    __shared__ __align__(16) float2 rxy[NPTS];            // 64 KB
    __shared__ __align__(16) float  rz[NPTS];             // 32 KB
    __shared__ __align__(16) float  smind[NPTS];          // 32 KB
    __shared__ __align__(8)  unsigned long long cellkey[NCELL];   // 4 KB
    __shared__ unsigned short sridx[NPTS];                // 16 KB
    __shared__ int   cellstart[NCELL + 1];
    __shared__ int   coff[NCELL];
    __shared__ int   clist[NCELL];
    __shared__ unsigned long long s_bk[8];

    // ---------------- setup: histogram -> prefix -> scatter ----------------
    coff[t] = 0;
    __syncthreads();
    for (int i = 0; i < 16; ++i) {
        int p = (i << 9) + t;
        float xx = pb[3 * p + 0], yy = pb[3 * p + 1], zz = pb[3 * p + 2];
        int ix = min((int)(xx * 8.0f), 7);   // clamp: x just below 1.0 can
        int iy = min((int)(yy * 8.0f), 7);   // round x*8 up to 8.0
        int iz = min((int)(zz * 8.0f), 7);
        atomicAdd(&coff[(iz << 6) | (iy << 3) | ix], 1);
    }
    __syncthreads();
    if (t == 0) {
        int acc = 0;
        for (int q = 0; q < NCELL; ++q) { cellstart[q] = acc; acc += coff[q]; }
        cellstart[NCELL] = acc;
    }
    __syncthreads();
    coff[t] = 0;
    __syncthreads();
    for (int i = 0; i < 16; ++i) {
        int p = (i << 9) + t;
        float xx = pb[3 * p + 0], yy = pb[3 * p + 1], zz = pb[3 * p + 2];
        int ix = min((int)(xx * 8.0f), 7);
        int iy = min((int)(yy * 8.0f), 7);
        int iz = min((int)(zz * 8.0f), 7);
        int cid = (iz << 6) | (iy << 3) | ix;
        int slot = cellstart[cid] + atomicAdd(&coff[cid], 1);
        rxy[slot] = make_float2(xx, yy);
        rz[slot] = zz;
        sridx[slot] = (unsigned short)p;
        smind[slot] = 1e30f;
    }
    __syncthreads();

    float lx = pb[0], ly = pb[1], lz = pb[2];   // first centroid = point 0

    // ======================= DENSE phase (all waves) =======================
    for (int m = 0; m < S_DENSE; ++m) {
        if (t == 0) {
            float* o = pos_s + (b * MCENT + m) * 3;
            o[0] = lx; o[1] = ly; o[2] = lz;
        }
        // full update, 2 points per float4/float2 group
#pragma unroll
        for (int i = 0; i < 8; ++i) {
            int g = (i << 9) + t;      // pair index 0..4095
            float4 xy2 = ((const float4*)rxy)[g];
            float2 zz2 = ((const float2*)rz)[g];
            float2 mm  = ((const float2*)smind)[g];
            mm.x = fminf(mm.x, dist2(xy2.x, xy2.y, zz2.x, lx, ly, lz));
            mm.y = fminf(mm.y, dist2(xy2.z, xy2.w, zz2.y, lx, ly, lz));
            ((float2*)smind)[g] = mm;
        }
        __syncthreads();                                    // d1
        // per-cell argmax (thread t scans cell t) -> u64 key in registers
        int s0 = cellstart[t], e0 = cellstart[t + 1];
        float red = 0.0f; int rarg = 0x7FFFFFFF;
        for (int j = s0; j < e0; ++j) {
            float mn = smind[j];
            int arg = (((int)sridx[j]) << 13) | j;
            bool tk = (mn > red) || (mn == red && arg < rarg);
            red = tk ? mn : red; rarg = tk ? arg : rarg;
        }
        unsigned long long bk = packkey(red, rarg);
        if (m + 1 == S_DENSE) cellkey[t] = bk;   // handoff state
        // 64-lane u64 DPP max (result valid in lane 63)
#define KSTEP(C_) { unsigned int klo = (unsigned int)bk;                      \
                    unsigned int khi = (unsigned int)(bk >> 32);              \
                    unsigned int olo = (unsigned int)dppi<C_>((int)klo);      \
                    unsigned int ohi = (unsigned int)dppi<C_>((int)khi);      \
                    unsigned long long ok =                                   \
                        ((unsigned long long)ohi << 32) | olo;                \
                    bk = ok > bk ? ok : bk; }
        KSTEP(0xB1) KSTEP(0x4E) KSTEP(0x141)
        KSTEP(0x140) KSTEP(0x142) KSTEP(0x143)
        if (l == 63) s_bk[w] = bk;
        __syncthreads();                                    // d2
        unsigned long long gk = s_bk[0];
#pragma unroll
        for (int q = 1; q < 8; ++q) { unsigned long long o = s_bk[q]; gk = o > gk ? o : gk; }
        int ga = 0x7FFFFFFF - (int)(unsigned int)(gk & 0xFFFFFFFFull);
        int jw = ga & 8191;
        float2 nxy = rxy[jw];
        lx = nxy.x; ly = nxy.y; lz = rz[jw];
    }
    __syncthreads();                    // cellkey visible to wave 0
    if (w != 0) return;                 // waves 1..7 exit; wave 0 barrier-free

    // ======================= SPARSE phase (wave 0) =========================
    const int lq = l & 15;              // lane-in-quarter
    // preload per-slot cell ranges + box coords (lane l owns c=(z<<6)|(l^z))
    int   cs[8], ce[8];
    float blox[8];
    const float bloy = (float)(l >> 3) * 0.125f;   // (l^z)>>3 == l>>3 (z<8)
#pragma unroll
    for (int z = 0; z < 8; ++z) {
        int c = (z << 6) | (l ^ z);
        cs[z] = cellstart[c];
        ce[z] = cellstart[c + 1];
        blox[z] = (float)((l ^ z) & 7) * 0.125f;
    }

    for (int m = S_DENSE; m < MCENT; ++m) {
        if (l == 0) {
            float* o = pos_s + (b * MCENT + m) * 3;
            o[0] = lx; o[1] = ly; o[2] = lz;
        }
        if (m + 1 == MCENT) break;

        // ---- prune + ballot-compact (register boxes vs cellkey hi word)
        int nu = 0;
#pragma unroll
        for (int z = 0; z < 8; ++z) {
            int c = (z << 6) | (l ^ z);
            float cmx = __uint_as_float(
                ((const unsigned int*)cellkey)[2 * c + 1]);
            float bz = (float)z * 0.125f;
            float dxm = fmaxf(fmaxf(blox[z] - lx, lx - (blox[z] + 0.125f)), 0.f);
            float dym = fmaxf(fmaxf(bloy - ly, ly - (bloy + 0.125f)), 0.f);
            float dzm = fmaxf(fmaxf(bz - lz, lz - (bz + 0.125f)), 0.f);
            float lb2 = fmaf(dxm, dxm, fmaf(dym, dym, dzm * dzm)) * 0.9999f;
            bool sv = lb2 < cmx;        // empty cell: cmx==+0.0 -> false
            unsigned long long mk = __ballot(sv);
            if (sv) clist[nu + __popcll(mk & ((1ull << l) - 1ull))] = c;
            nu += (int)__popcll(mk);    // lane-uniform
        }

        // ---- update passes: one 16-lane quarter per surviving cell
        for (int r = 0; r < nu; r += 4) {
            int idx = r + (l >> 4);
            idx = idx < nu ? idx : nu - 1;      // dup tail: idempotent
            int cid = clist[idx];
            int s0 = cellstart[cid], e0 = cellstart[cid + 1];
            float red = 0.0f; int rarg = 0x7FFFFFFF;
            for (int j = s0 + lq; j < e0; j += 16) {
                float2 xy = rxy[j]; float zz = rz[j];
                float d = dist2(xy.x, xy.y, zz, lx, ly, lz);
                float mn = fminf(smind[j], d);
                smind[j] = mn;
                int arg = (((int)sridx[j]) << 13) | j;
                bool tk = (mn > red) || (mn == red && arg < rarg);
                red = tk ? mn : red; rarg = tk ? arg : rarg;
            }
            // 16-lane DPP argmax (stays within one DPP row)
#define ASTEP(C_) { float ov = dppf<C_>(red); int oa = dppi<C_>(rarg);        \
                    bool tk = (ov > red) || (ov == red && oa < rarg);         \
                    red = tk ? ov : red; rarg = tk ? oa : rarg; }
            ASTEP(0xB1) ASTEP(0x4E) ASTEP(0x141) ASTEP(0x140)
#undef ASTEP
            if (lq == 0) cellkey[cid] = packkey(red, rarg);
        }

        // ---- global argmax: 8 keys/lane + 6-step u64 DPP max -> lane 63
        unsigned long long bk = 0;
#pragma unroll
        for (int z = 0; z < 8; ++z) {
            unsigned long long k = cellkey[(z << 6) | (l ^ z)];
            bk = k > bk ? k : bk;
        }
        KSTEP(0xB1) KSTEP(0x4E) KSTEP(0x141)
        KSTEP(0x140) KSTEP(0x142) KSTEP(0x143)
        unsigned int rlo = (unsigned int)__builtin_amdgcn_readlane(
            (int)(unsigned int)bk, 63);
        int ga = 0x7FFFFFFF - (int)rlo;
        int jw = ga & 8191;
        float2 nxy = rxy[jw];
        lx = nxy.x; ly = nxy.y; lz = rz[jw];
    }
#undef KSTEP
}

// ---------------------------------------------------------------------------
// Kernel 2: exact top-64 (by (d2, idx) u64 key) within ball r=0.4 via
// histogram radix-select + O(C^2) exact ranking. (unchanged)
// ---------------------------------------------------------------------------
#define KNN_CAP 320

__global__ __launch_bounds__(256) void knn_kernel(const float* __restrict__ pos,
                                                  const float* __restrict__ pos_s,
                                                  int* __restrict__ nidx,
                                                  float* __restrict__ nd2,
                                                  int* __restrict__ ncnt) {
    const int c = blockIdx.x;
    const int b = c >> 11;              // c / MCENT
    const float* pb = pos + b * NPTS * 3;
    const int t = threadIdx.x;

    const float cx = pos_s[c * 3 + 0];
    const float cy = pos_s[c * 3 + 1];
    const float cz = pos_s[c * 3 + 2];

    __shared__ int hist[64];
    __shared__ int s_B64, s_total, s_cnt;
    __shared__ unsigned long long cand[KNN_CAP];

    if (t < 64) hist[t] = 0;
    if (t == 0) s_cnt = 0;
    __syncthreads();

    float d2r[32];
#pragma unroll
    for (int i = 0; i < 32; ++i) {
        int p = (i << 8) + t;
        float d2 = dist2(cx, cy, cz, pb[3 * p + 0], pb[3 * p + 1], pb[3 * p + 2]);
        d2r[i] = d2;
        if (d2 <= 0.16f) {
            int bkt = (int)(d2 * 400.0f);      // monotone; 0.16f*400 < 64
            bkt = bkt > 63 ? 63 : bkt;
            atomicAdd(&hist[bkt], 1);
        }
    }
    __syncthreads();

    if (t == 0) {
        int cum = 0, B = -1;
#pragma unroll
        for (int j = 0; j < 64; ++j) {
            cum += hist[j];
            if (B < 0 && cum >= 64) B = j;
        }
        s_B64 = (B < 0) ? 63 : B;
        s_total = cum;
    }
    __syncthreads();

    const int B64 = s_B64;
#pragma unroll
    for (int i = 0; i < 32; ++i) {
        float d2 = d2r[i];
        if (d2 <= 0.16f) {
            int bkt = (int)(d2 * 400.0f);
            bkt = bkt > 63 ? 63 : bkt;
            if (bkt <= B64) {
                int slot = atomicAdd(&s_cnt, 1);
                if (slot < KNN_CAP) {
                    int p = (i << 8) + t;
                    cand[slot] = ((unsigned long long)__float_as_uint(d2) << 32)
                                 | (unsigned int)p;
                }
            }
        }
    }
    __syncthreads();

    const int C = s_cnt < KNN_CAP ? s_cnt : KNN_CAP;
    for (int tc = t; tc < C; tc += 256) {
        unsigned long long my = cand[tc];
        int rank = 0;
        for (int j = 0; j < C; ++j) rank += (cand[j] < my) ? 1 : 0;
        if (rank < KMAX) {
            nidx[c * KMAX + rank] = (int)(my & 0xffffffffULL);
            nd2[c * KMAX + rank]  = __uint_as_float((unsigned int)(my >> 32));
        }
    }
    if (t == 0) ncnt[c] = s_total < KMAX ? s_total : KMAX;
}

// ---------------------------------------------------------------------------
// Kernel 3: fused gather + 2-layer MLP + masked max per centroid. (unchanged)
// ---------------------------------------------------------------------------
template <int K, int C1, int C2, int OUTOFF>
__global__ __launch_bounds__(256, 2) void mlp_kernel(
        const float* __restrict__ x, const float* __restrict__ pos,
        const float* __restrict__ pos_s,
        const int* __restrict__ nidx, const float* __restrict__ nd2,
        const int* __restrict__ ncnt,
        const float* __restrict__ W1, const float* __restrict__ B1,
        const float* __restrict__ W2, const float* __restrict__ B2,
        float* __restrict__ out, float r2) {
    const int c = blockIdx.x;
    const int b = c >> 11;
    const int t = threadIdx.x;

    __shared__ float F[K][68];      // [K][67] padded to 17 float4
    __shared__ float H[K][C1];
    __shared__ int   s_nbr[K];
    __shared__ int   s_valid[K];
    __shared__ float s_ctr[3];

    const int cntAll = ncnt[c];
    const int cnt = cntAll < K ? cntAll : K;
    if (t < 3) s_ctr[t] = pos_s[c * 3 + t];
    if (t < K) {
        bool ok = t < cnt;
        s_nbr[t]   = ok ? nidx[c * KMAX + t] : 0;
        s_valid[t] = ok && (nd2[c * KMAX + t] <= r2);
    }
    __syncthreads();

    // gather features: F[k] = [ x[nbr] (64) | pos[nbr]-ctr (3) | 0 pad ]
    for (int e = t; e < K * 17; e += 256) {
        int k = e / 17, q = e % 17;
        int nbr = s_nbr[k];
        bool ok = k < cnt;
        float4 val;
        if (q < 16) {
            const float4* xr = (const float4*)(x + (b * NPTS + nbr) * CFEAT);
            if (ok) val = xr[q];
            else { val.x = 0.f; val.y = 0.f; val.z = 0.f; val.w = 0.f; }
        } else {
            const float* pp = pos + (b * NPTS + nbr) * 3;
            val.x = ok ? pp[0] - s_ctr[0] : 0.f;
            val.y = ok ? pp[1] - s_ctr[1] : 0.f;
            val.z = ok ? pp[2] - s_ctr[2] : 0.f;
            val.w = 0.f;
        }
        ((float4*)&F[k][0])[q] = val;
    }
    __syncthreads();

    // layer 1: H[k][j] = relu(B1[j] + F[k]·W1[:,j])
    {
        constexpr int STR = 256 / C1;
        const int j  = t % C1;
        const int kb = t / C1;
        float w1c[68];
#pragma unroll
        for (int i = 0; i < 67; ++i) w1c[i] = W1[i * C1 + j];
        w1c[67] = 0.f;
        const float bj = B1[j];
        for (int k = kb; k < K; k += STR) {
            float acc = bj;
            const float4* fr = (const float4*)&F[k][0];
#pragma unroll
            for (int q = 0; q < 17; ++q) {
                float4 f = fr[q];
                acc = fmaf(f.x, w1c[4 * q + 0], acc);
                acc = fmaf(f.y, w1c[4 * q + 1], acc);
                acc = fmaf(f.z, w1c[4 * q + 2], acc);
                acc = fmaf(f.w, w1c[4 * q + 3], acc);
            }
            H[k][j] = fmaxf(acc, 0.f);
        }
    }
    __syncthreads();

    // layer 2 + masked max over neighbors
    if constexpr (C2 == 256) {
        const int j2 = t;
        float w2c[C1];
#pragma unroll
        for (int i = 0; i < C1; ++i) w2c[i] = W2[i * C2 + j2];
        const float bj = B2[j2];
        float omax = NEGV;
        for (int k = 0; k < K; ++k) {
            if (!s_valid[k]) continue;          // uniform branch
            float acc = bj;
            const float4* hr = (const float4*)&H[k][0];
#pragma unroll
            for (int q = 0; q < C1 / 4; ++q) {
                float4 h = hr[q];
                acc = fmaf(h.x, w2c[4 * q + 0], acc);
                acc = fmaf(h.y, w2c[4 * q + 1], acc);
                acc = fmaf(h.z, w2c[4 * q + 2], acc);
                acc = fmaf(h.w, w2c[4 * q + 3], acc);
            }
            omax = fmaxf(omax, fmaxf(acc, 0.f));
        }
        out[c * 384 + OUTOFF + j2] = omax;
    } else {
        // C2 == 128: 2 thread-groups split the k range, combine via LDS
        const int j2 = t % C2;
        const int g  = t / C2;
        __shared__ float pm[256];
        float w2c[C1];
#pragma unroll
        for (int i = 0; i < C1; ++i) w2c[i] = W2[i * C2 + j2];
        const float bj = B2[j2];
        float omax = NEGV;
        for (int k = g; k < K; k += 2) {
            if (!s_valid[k]) continue;
            float acc = bj;
            const float4* hr = (const float4*)&H[k][0];
#pragma unroll
            for (int q = 0; q < C1 / 4; ++q) {
                float4 h = hr[q];
                acc = fmaf(h.x, w2c[4 * q + 0], acc);
                acc = fmaf(h.y, w2c[4 * q + 1], acc);
                acc = fmaf(h.z, w2c[4 * q + 2], acc);
                acc = fmaf(h.w, w2c[4 * q + 3], acc);
            }
            omax = fmaxf(omax, fmaxf(acc, 0.f));
        }
        pm[t] = omax;
        __syncthreads();
        if (t < C2) out[c * 384 + OUTOFF + t] = fmaxf(pm[t], pm[t + C2]);
    }
}

extern "C" void kernel_launch(void* const* d_in, const int* in_sizes, int n_in,
                              void* d_out, int out_size, void* d_ws, size_t ws_size,
                              hipStream_t stream) {
    const float* x    = (const float*)d_in[0];
    const float* pos  = (const float*)d_in[1];
    const float* w1_0 = (const float*)d_in[2];
    const float* b1_0 = (const float*)d_in[3];
    const float* w1_1 = (const float*)d_in[4];
    const float* b1_1 = (const float*)d_in[5];
    const float* w2_0 = (const float*)d_in[6];
    const float* b2_0 = (const float*)d_in[7];
    const float* w2_1 = (const float*)d_in[8];
    const float* b2_1 = (const float*)d_in[9];

    float* out   = (float*)d_out;
    float* pos_s = out + NCENT * 384;          // second output, written by FPS

    char* ws = (char*)d_ws;
    int*   ncnt = (int*)ws;                                   // NCENT ints
    int*   nidx = (int*)(ws + NCENT * 4);                     // NCENT*64 ints
    float* nd2  = (float*)(ws + NCENT * 4 + NCENT * KMAX * 4);// NCENT*64 floats

    fps_kernel<<<BATCH, FPS_T, 0, stream>>>(pos, pos_s);
    knn_kernel<<<NCENT, 256, 0, stream>>>(pos, pos_s, nidx, nd2, ncnt);
    mlp_kernel<32, 64, 128, 0><<<NCENT, 256, 0, stream>>>(
        x, pos, pos_s, nidx, nd2, ncnt, w1_0, b1_0, w1_1, b1_1, out, 0.04f);
    mlp_kernel<64, 128, 256, 128><<<NCENT, 256, 0, stream>>>(
        x, pos, pos_s, nidx, nd2, ncnt, w2_0, b2_0, w2_1, b2_1, out, 0.16f);
}